// Round 7
// baseline (5608.231 us; speedup 1.0000x reference)
//
#include <hip/hip_runtime.h>
#include <hip/hip_bf16.h>
#include <math.h>

// ---------------------------------------------------------------------------
// WaveNet inference, fp32, right-aligned suffix computation.
// Derivations (verified rounds 2-5, absmax 2.4e-4):
//  - dilate() batch-folding == time-domain dilated 2-tap conv: out[t] uses
//    taps X[t], X[t+d]; residual adds X[t+d].
//  - x_skip is OVERWRITTEN each layer -> only layer 39's skip matters, and
//    its input is h = tanh*sigmoid (BEFORE the residual conv).
//  - output needs only the trailing 4096+4092=8188 samples of start conv.
// Round 7: r6's coop kernel never ran (output all-zero, API-level rejection
// never checked). Now: grid-agnostic coop kernel (chunk-strided, arrival
// count from gridDim), attempt grid 1024 -> 512, CHECK ERRORS, fall back to
// the r5 per-layer sequence (passed, 954us) if coop is unavailable.
// ---------------------------------------------------------------------------

#define TS   8192
#define T0   8188
#define NB   8
#define TOUT 4096

// workspace layout (float offsets)
#define OFF_WBLOB 0                      // 40 * 5120  (wf[ic][k][oc], wg, wr[ic][oc])
#define OFF_ST    204800                 // start_w^T  [ic][oc]
#define OFF_SK    212992                 // skip_w[39]^T [dc][sc]
#define OFF_E1T   221184                 // end1^T [sc][ec]
#define OFF_E2T   286720                 // end2^T [ec][cc]
#define OFF_XA    352256                 // NB*32*TS
#define OFF_XB    (OFF_XA + NB*32*TS)
#define OFF_H1    (OFF_XB + NB*32*TS)    // NB*256*TOUT
#define OFF_E1    (OFF_H1 + NB*256*TOUT)
#define OFF_CNT   (OFF_E1 + NB*256*TOUT) // 43*8 uint barrier counters
#define NBAR      43

__device__ __forceinline__ float tanh_fast(float x) {
    float e = __expf(2.0f * x);
    return 1.0f - 2.0f / (e + 1.0f);
}
__device__ __forceinline__ float sigmoid_fast(float x) {
    return 1.0f / (1.0f + __expf(-x));
}

// per-b barrier: nb blocks of batch b rendezvous. Release add publishes this
// block's stores; relaxed spin; acquire fence before next phase's reads.
__device__ __forceinline__ void pb_barrier(unsigned* cnt, int idx, unsigned nb) {
    __syncthreads();
    if (threadIdx.x == 0) {
        __hip_atomic_fetch_add(&cnt[idx], 1u, __ATOMIC_RELEASE, __HIP_MEMORY_SCOPE_AGENT);
        while (__hip_atomic_load(&cnt[idx], __ATOMIC_RELAXED, __HIP_MEMORY_SCOPE_AGENT) < nb)
            __builtin_amdgcn_s_sleep(2);
    }
    __syncthreads();
    __builtin_amdgcn_fence(__ATOMIC_ACQUIRE, "agent");
}

// ---------------------------------------------------------------------------
__global__ void repack_kernel(const float* __restrict__ start_w,
                              const float* __restrict__ filter_w,
                              const float* __restrict__ gate_w,
                              const float* __restrict__ residual_w,
                              const float* __restrict__ skip_w,
                              const float* __restrict__ end1_w,
                              const float* __restrict__ end2_w,
                              float* __restrict__ ws) {
    int id = blockIdx.x * 256 + threadIdx.x;
    if (id < 204800) {
        int l = id / 5120, r = id % 5120;
        float v;
        if (r < 4096) {                      // wf then wg: [ic][k][oc]
            const float* src = (r < 2048) ? filter_w : gate_w;
            int rr = r & 2047;
            int ic = rr >> 6, k = (rr >> 5) & 1, oc = rr & 31;
            v = src[((l * 32 + oc) * 32 + ic) * 2 + k];
        } else {                             // wr: [ic][oc]
            int rr = r - 4096;
            int ic = rr >> 5, oc = rr & 31;
            v = residual_w[(l * 32 + oc) * 32 + ic];
        }
        ws[OFF_WBLOB + id] = v;
    } else if (id < 204800 + 8192) {
        int r = id - 204800;
        int ic = r >> 5, oc = r & 31;
        ws[OFF_ST + r] = start_w[oc * 256 + ic];
    } else if (id < 212992 + 8192) {
        int r = id - 212992;
        int dc = r >> 8, sc = r & 255;
        ws[OFF_SK + r] = skip_w[(39 * 256 + sc) * 32 + dc];
    } else if (id < 221184 + 65536) {
        int r = id - 221184;
        int sc = r >> 8, ec = r & 255;
        ws[OFF_E1T + r] = end1_w[ec * 256 + sc];
    } else if (id < 286720 + 65536) {
        int r = id - 286720;
        int ec = r >> 8, cc = r & 255;
        ws[OFF_E2T + r] = end2_w[cc * 256 + ec];
    }
}

// ---------------------------------------------------------------------------
// Cooperative whole-network kernel. Block = 256 thr (4 waves). Block id ->
// (b = id&7, c0 = id>>3); NC = gridDim.x/8 blocks per batch element; each
// block strides over 64-wide t-chunks. Barriers are per-b.
__global__ __launch_bounds__(256, 4) void wavenet_all(
        const float* __restrict__ x_input,
        float* __restrict__ ws,
        const float* __restrict__ e1b,
        const float* __restrict__ e2b,
        float* __restrict__ out)
{
    __shared__ float A[32][64], C[32][64], Hs[32][64];
    const int tid = threadIdx.x;
    const int tx  = tid & 63;
    const int cg  = __builtin_amdgcn_readfirstlane(tid >> 6);   // 0..3
    const int b   = blockIdx.x & 7;
    const int c0  = blockIdx.x >> 3;
    const unsigned NC = gridDim.x >> 3;
    unsigned* cnt = (unsigned*)(ws + OFF_CNT);
    int bar = 0;

    // ===== start conv =====
#pragma unroll 1
    for (int cc = c0; cc * 64 < T0; cc += NC) {
        const int t0 = cc * 64;
        const float* xb = x_input + (size_t)b * 256 * 16384 + (16384 - T0);
        const float* st = ws + OFF_ST + cg * 8;
        float acc[8];
#pragma unroll
        for (int o = 0; o < 8; o++) acc[o] = 0.f;
        for (int k0 = 0; k0 < 256; k0 += 32) {
            __syncthreads();
            for (int i = tid; i < 2048; i += 256) {
                int ic = i >> 6, tt = i & 63;
                int tg = t0 + tt;
                A[ic][tt] = (tg < T0) ? xb[(size_t)(k0 + ic) * 16384 + tg] : 0.f;
            }
            __syncthreads();
            const float* wb = st + (size_t)k0 * 32;
#pragma unroll 8
            for (int ic = 0; ic < 32; ic++) {
                float xv = A[ic][tx];
                const float* w = wb + ic * 32;
#pragma unroll
                for (int o = 0; o < 8; o++) acc[o] = fmaf(w[o], xv, acc[o]);
            }
        }
        if (t0 + tx < T0) {
            float* xo = ws + OFF_XA + ((size_t)(b * 32) + cg * 8) * TS + t0 + tx;
#pragma unroll
            for (int o = 0; o < 8; o++) xo[o * TS] = acc[o];
        }
    }
    pb_barrier(cnt, (bar++) * 8 + b, NC);

    // ===== 40 layers =====
    int Tin = T0;
#pragma unroll 1
    for (int l = 0; l < 40; l++) {
        const int e = l - (l / 10) * 10;
        const int d = 1 << e;
        const int To = Tin - d;
        const float* xin  = ws + ((l & 1) ? OFF_XB : OFF_XA);
        float*       xout = ws + ((l & 1) ? OFF_XA : OFF_XB);
        const float* wl = ws + OFF_WBLOB + (size_t)l * 5120;

#pragma unroll 1
        for (int cc = c0; cc * 64 < To; cc += NC) {
            const int t0 = cc * 64;
            const float* xb2 = xin + (size_t)(b * 32) * TS + t0;
            __syncthreads();
            for (int i = tid; i < 2048; i += 256) {
                int ch = i >> 6, tt = i & 63;
                A[ch][tt] = xb2[(size_t)ch * TS + tt];
                C[ch][tt] = xb2[(size_t)ch * TS + d + tt];
            }
            __syncthreads();

            const float* wf = wl +        cg * 8;
            const float* wg = wl + 2048 + cg * 8;
            float accf[8], accg[8];
#pragma unroll
            for (int o = 0; o < 8; o++) { accf[o] = 0.f; accg[o] = 0.f; }
#pragma unroll 8
            for (int ic = 0; ic < 32; ic++) {
                float a  = A[ic][tx];
                float cv = C[ic][tx];
                const float* w0 = wf + ic * 64;
                const float* w1 = wg + ic * 64;
#pragma unroll
                for (int o = 0; o < 8; o++) accf[o] = fmaf(w0[o],      a,  accf[o]);
#pragma unroll
                for (int o = 0; o < 8; o++) accf[o] = fmaf(w0[32 + o], cv, accf[o]);
#pragma unroll
                for (int o = 0; o < 8; o++) accg[o] = fmaf(w1[o],      a,  accg[o]);
#pragma unroll
                for (int o = 0; o < 8; o++) accg[o] = fmaf(w1[32 + o], cv, accg[o]);
            }
            float h[8];
#pragma unroll
            for (int o = 0; o < 8; o++) h[o] = tanh_fast(accf[o]) * sigmoid_fast(accg[o]);

            if (l == 39) {                    // only h consumed (skip conv input)
                if (t0 + tx < To) {
                    float* xo = xout + ((size_t)(b * 32) + cg * 8) * TS + t0 + tx;
#pragma unroll
                    for (int o = 0; o < 8; o++) xo[o * TS] = h[o];
                }
            } else {
#pragma unroll
                for (int o = 0; o < 8; o++) Hs[cg * 8 + o][tx] = h[o];
                __syncthreads();
                const float* wr = wl + 4096 + cg * 8;
                float acc[8];
#pragma unroll
                for (int o = 0; o < 8; o++) acc[o] = C[cg * 8 + o][tx];  // residual X[t+d]
#pragma unroll 8
                for (int ic = 0; ic < 32; ic++) {
                    float hv = Hs[ic][tx];
#pragma unroll
                    for (int o = 0; o < 8; o++) acc[o] = fmaf(wr[ic * 32 + o], hv, acc[o]);
                }
                if (t0 + tx < To) {
                    float* xo = xout + ((size_t)(b * 32) + cg * 8) * TS + t0 + tx;
#pragma unroll
                    for (int o = 0; o < 8; o++) xo[o * TS] = acc[o];
                }
            }
        }
        pb_barrier(cnt, (bar++) * 8 + b, NC);
        Tin = To;
    }
    // h of layer 39 in XA (l=39 odd -> xout = XA); Tin == 4096

    // ===== skip conv + relu (K=32) =====
#pragma unroll 1
    for (int cc = c0; cc < 64; cc += NC) {
        const int te = cc * 64;
        const float* xb3 = ws + OFF_XA + (size_t)(b * 32) * TS + te;
        __syncthreads();
        for (int i = tid; i < 2048; i += 256) {
            int ch = i >> 6, tt = i & 63;
            A[ch][tt] = xb3[(size_t)ch * TS + tt];
        }
        __syncthreads();
        const float* wb = ws + OFF_SK + cg * 64;
        float acc[64];
#pragma unroll
        for (int j = 0; j < 64; j++) acc[j] = 0.f;
#pragma unroll 4
        for (int dc = 0; dc < 32; dc++) {
            float xv = A[dc][tx];
            const float* w = wb + dc * 256;
#pragma unroll
            for (int j = 0; j < 64; j++) acc[j] = fmaf(w[j], xv, acc[j]);
        }
        float* ho = ws + OFF_H1 + ((size_t)(b * 256) + cg * 64) * TOUT + te + tx;
#pragma unroll
        for (int j = 0; j < 64; j++) ho[j * TOUT] = fmaxf(acc[j], 0.f);
    }
    pb_barrier(cnt, (bar++) * 8 + b, NC);

    // ===== end1 + bias + relu (K=256 staged in chunks of 32) =====
#pragma unroll 1
    for (int cc = c0; cc < 64; cc += NC) {
        const int te = cc * 64;
        float acc[64];
#pragma unroll
        for (int j = 0; j < 64; j++) acc[j] = e1b[cg * 64 + j];
        for (int k0 = 0; k0 < 256; k0 += 32) {
            __syncthreads();
            const float* hp = ws + OFF_H1 + ((size_t)(b * 256) + k0) * TOUT + te;
            for (int i = tid; i < 2048; i += 256) {
                int sc = i >> 6, tt = i & 63;
                A[sc][tt] = hp[(size_t)sc * TOUT + tt];
            }
            __syncthreads();
            const float* wb = ws + OFF_E1T + (size_t)k0 * 256 + cg * 64;
#pragma unroll 4
            for (int sc = 0; sc < 32; sc++) {
                float xv = A[sc][tx];
                const float* w = wb + sc * 256;
#pragma unroll
                for (int j = 0; j < 64; j++) acc[j] = fmaf(w[j], xv, acc[j]);
            }
        }
        float* ep = ws + OFF_E1 + ((size_t)(b * 256) + cg * 64) * TOUT + te + tx;
#pragma unroll
        for (int j = 0; j < 64; j++) ep[j * TOUT] = fmaxf(acc[j], 0.f);
    }
    pb_barrier(cnt, (bar++) * 8 + b, NC);

    // ===== end2 + bias, transposed store =====
#pragma unroll 1
    for (int cc = c0; cc < 64; cc += NC) {
        const int te = cc * 64;
        float acc[64];
#pragma unroll
        for (int j = 0; j < 64; j++) acc[j] = e2b[cg * 64 + j];
        for (int k0 = 0; k0 < 256; k0 += 32) {
            __syncthreads();
            const float* epi = ws + OFF_E1 + ((size_t)(b * 256) + k0) * TOUT + te;
            for (int i = tid; i < 2048; i += 256) {
                int ec = i >> 6, tt = i & 63;
                A[ec][tt] = epi[(size_t)ec * TOUT + tt];
            }
            __syncthreads();
            const float* wb = ws + OFF_E2T + (size_t)k0 * 256 + cg * 64;
#pragma unroll 4
            for (int ec = 0; ec < 32; ec++) {
                float xv = A[ec][tx];
                const float* w = wb + ec * 256;
#pragma unroll
                for (int j = 0; j < 64; j++) acc[j] = fmaf(w[j], xv, acc[j]);
            }
        }
        float* op = out + ((size_t)(b * TOUT + te + tx)) * 256 + cg * 64;
#pragma unroll
        for (int j = 0; j < 16; j++)
            ((float4*)op)[j] = make_float4(acc[4*j], acc[4*j+1], acc[4*j+2], acc[4*j+3]);
    }
}

// ===========================================================================
// Fallback path: r5's verified per-layer kernels (passed at 954us).
// ===========================================================================
__global__ __launch_bounds__(512) void start_kernel(const float* __restrict__ xin,
                                                    const float* __restrict__ st,
                                                    float* __restrict__ xout) {
    __shared__ float S[32][64];
    int tx = threadIdx.x, ty = threadIdx.y;
    int cg = __builtin_amdgcn_readfirstlane(ty);
    int tid = ty * 64 + tx;
    int t0 = blockIdx.x * 64;
    int b  = blockIdx.y;
    int t  = t0 + tx;
    const float* xb = xin + (size_t)b * 256 * 16384 + (16384 - T0);
    float acc[4] = {0.f, 0.f, 0.f, 0.f};
    for (int k0 = 0; k0 < 256; k0 += 32) {
        if (k0) __syncthreads();
        for (int i = tid; i < 2048; i += 512) {
            int ic = i >> 6, tt = i & 63;
            int tg = t0 + tt;
            S[ic][tt] = (tg < T0) ? xb[(size_t)(k0 + ic) * 16384 + tg] : 0.f;
        }
        __syncthreads();
        const float* wbase = st + (size_t)k0 * 32 + cg * 4;
#pragma unroll 8
        for (int i = 0; i < 32; i++) {
            float xv = S[i][tx];
            const float* w = wbase + i * 32;
#pragma unroll
            for (int o = 0; o < 4; o++) acc[o] = fmaf(w[o], xv, acc[o]);
        }
    }
    if (t < T0) {
        float* xo = xout + ((size_t)(b * 32) + cg * 4) * TS + t;
#pragma unroll
        for (int o = 0; o < 4; o++) xo[o * TS] = acc[o];
    }
}

__global__ __launch_bounds__(512) void layer_kernel(const float* __restrict__ xin,
                                                    float* __restrict__ xout,
                                                    const float* __restrict__ wl,
                                                    int d, int Tout, int last) {
    __shared__ float A[32][64], C[32][64], Hs[32][64];
    int tx = threadIdx.x, ty = threadIdx.y;
    int cg = __builtin_amdgcn_readfirstlane(ty);
    int tid = ty * 64 + tx;
    int t0 = blockIdx.x * 64;
    int b  = blockIdx.y;
    int t  = t0 + tx;
    const float* xb = xin + (size_t)(b * 32) * TS;
    for (int i = tid; i < 2048; i += 512) {
        int ch = i >> 6, tt = i & 63;
        A[ch][tt] = xb[(size_t)ch * TS + t0 + tt];
        C[ch][tt] = xb[(size_t)ch * TS + t0 + d + tt];
    }
    __syncthreads();

    const float* wf = wl +        cg * 4;
    const float* wg = wl + 2048 + cg * 4;
    const float* wr = wl + 4096 + cg * 4;

    float accf[4] = {0.f, 0.f, 0.f, 0.f}, accg[4] = {0.f, 0.f, 0.f, 0.f};
#pragma unroll 8
    for (int ic = 0; ic < 32; ic++) {
        float a = A[ic][tx];
        float c = C[ic][tx];
        const float* w0 = wf + ic * 64;
        const float* w1 = wg + ic * 64;
#pragma unroll
        for (int o = 0; o < 4; o++) accf[o] = fmaf(w0[o],      a, accf[o]);
#pragma unroll
        for (int o = 0; o < 4; o++) accf[o] = fmaf(w0[32 + o], c, accf[o]);
#pragma unroll
        for (int o = 0; o < 4; o++) accg[o] = fmaf(w1[o],      a, accg[o]);
#pragma unroll
        for (int o = 0; o < 4; o++) accg[o] = fmaf(w1[32 + o], c, accg[o]);
    }
    float h[4];
#pragma unroll
    for (int o = 0; o < 4; o++) h[o] = tanh_fast(accf[o]) * sigmoid_fast(accg[o]);

    if (last) {
        if (t < Tout) {
            float* xo = xout + ((size_t)(b * 32) + cg * 4) * TS + t;
#pragma unroll
            for (int o = 0; o < 4; o++) xo[o * TS] = h[o];
        }
        return;
    }
#pragma unroll
    for (int o = 0; o < 4; o++) Hs[cg * 4 + o][tx] = h[o];
    __syncthreads();
    float acc[4];
#pragma unroll
    for (int o = 0; o < 4; o++) acc[o] = C[cg * 4 + o][tx];
#pragma unroll 8
    for (int ic = 0; ic < 32; ic++) {
        float hv = Hs[ic][tx];
#pragma unroll
        for (int o = 0; o < 4; o++) acc[o] = fmaf(wr[ic * 32 + o], hv, acc[o]);
    }
    if (t < Tout) {
        float* xo = xout + ((size_t)(b * 32) + cg * 4) * TS + t;
#pragma unroll
        for (int o = 0; o < 4; o++) xo[o * TS] = acc[o];
    }
}

__global__ __launch_bounds__(512) void skip_kernel(const float* __restrict__ xin,
                                                   const float* __restrict__ sk,
                                                   float* __restrict__ h1) {
    __shared__ float S[32][64];
    int tx = threadIdx.x, ty = threadIdx.y;
    int cg = __builtin_amdgcn_readfirstlane(ty);
    int tid = ty * 64 + tx;
    int t0 = blockIdx.x * 64;
    int b  = blockIdx.y;
    int t  = t0 + tx;
    const float* xb = xin + (size_t)(b * 32) * TS;
    for (int i = tid; i < 2048; i += 512) {
        int ch = i >> 6, tt = i & 63;
        S[ch][tt] = xb[(size_t)ch * TS + t0 + tt];
    }
    __syncthreads();
    const float* wb = sk + cg * 32;
    float acc[32];
#pragma unroll
    for (int j = 0; j < 32; j++) acc[j] = 0.f;
#pragma unroll 4
    for (int dc = 0; dc < 32; dc++) {
        float xv = S[dc][tx];
        const float* w = wb + dc * 256;
#pragma unroll
        for (int j = 0; j < 32; j++) acc[j] = fmaf(w[j], xv, acc[j]);
    }
    float* ho = h1 + ((size_t)(b * 256) + cg * 32) * TOUT + t;
#pragma unroll
    for (int j = 0; j < 32; j++) ho[j * TOUT] = fmaxf(acc[j], 0.f);
}

__global__ __launch_bounds__(512) void end1_kernel(const float* __restrict__ h1,
                                                   const float* __restrict__ e1t,
                                                   const float* __restrict__ b1,
                                                   float* __restrict__ e1) {
    __shared__ float S[32][64];
    int tx = threadIdx.x, ty = threadIdx.y;
    int cg = __builtin_amdgcn_readfirstlane(ty);
    int tid = ty * 64 + tx;
    int t0 = blockIdx.x * 64;
    int b  = blockIdx.y;
    int t  = t0 + tx;
    const float* hp = h1 + (size_t)(b * 256) * TOUT;
    const float* wb = e1t + cg * 32;
    float acc[32];
#pragma unroll
    for (int j = 0; j < 32; j++) acc[j] = b1[cg * 32 + j];
    for (int k0 = 0; k0 < 256; k0 += 32) {
        if (k0) __syncthreads();
        for (int i = tid; i < 2048; i += 512) {
            int sc = i >> 6, tt = i & 63;
            S[sc][tt] = hp[(size_t)(k0 + sc) * TOUT + t0 + tt];
        }
        __syncthreads();
#pragma unroll 4
        for (int sc = 0; sc < 32; sc++) {
            float xv = S[sc][tx];
            const float* w = wb + (size_t)(k0 + sc) * 256;
#pragma unroll
            for (int j = 0; j < 32; j++) acc[j] = fmaf(w[j], xv, acc[j]);
        }
    }
    float* ep = e1 + ((size_t)(b * 256) + cg * 32) * TOUT + t;
#pragma unroll
    for (int j = 0; j < 32; j++) ep[j * TOUT] = fmaxf(acc[j], 0.f);
}

__global__ __launch_bounds__(512) void end2_kernel(const float* __restrict__ e1,
                                                   const float* __restrict__ e2t,
                                                   const float* __restrict__ b2,
                                                   float* __restrict__ out) {
    __shared__ float S[32][64];
    int tx = threadIdx.x, ty = threadIdx.y;
    int cg = __builtin_amdgcn_readfirstlane(ty);
    int tid = ty * 64 + tx;
    int t0 = blockIdx.x * 64;
    int b  = blockIdx.y;
    int t  = t0 + tx;
    const float* ep = e1 + (size_t)(b * 256) * TOUT;
    const float* wb = e2t + cg * 32;
    float acc[32];
#pragma unroll
    for (int j = 0; j < 32; j++) acc[j] = b2[cg * 32 + j];
    for (int k0 = 0; k0 < 256; k0 += 32) {
        if (k0) __syncthreads();
        for (int i = tid; i < 2048; i += 512) {
            int ec = i >> 6, tt = i & 63;
            S[ec][tt] = ep[(size_t)(k0 + ec) * TOUT + t0 + tt];
        }
        __syncthreads();
#pragma unroll 4
        for (int ec = 0; ec < 32; ec++) {
            float xv = S[ec][tx];
            const float* w = wb + (size_t)(k0 + ec) * 256;
#pragma unroll
            for (int j = 0; j < 32; j++) acc[j] = fmaf(w[j], xv, acc[j]);
        }
    }
    float* op = out + ((size_t)(b * TOUT + t)) * 256 + cg * 32;
#pragma unroll
    for (int j = 0; j < 8; j++)
        ((float4*)op)[j] = make_float4(acc[4*j], acc[4*j+1], acc[4*j+2], acc[4*j+3]);
}

// ---------------------------------------------------------------------------
extern "C" void kernel_launch(void* const* d_in, const int* in_sizes, int n_in,
                              void* d_out, int out_size, void* d_ws, size_t ws_size,
                              hipStream_t stream) {
    const float* x_input    = (const float*)d_in[0];
    const float* start_w    = (const float*)d_in[1];
    const float* filter_w   = (const float*)d_in[2];
    const float* gate_w     = (const float*)d_in[3];
    const float* residual_w = (const float*)d_in[4];
    const float* skip_w     = (const float*)d_in[5];
    const float* end1_w     = (const float*)d_in[6];
    const float* end1_b     = (const float*)d_in[7];
    const float* end2_w     = (const float*)d_in[8];
    const float* end2_b     = (const float*)d_in[9];
    float* ws  = (float*)d_ws;
    float* out = (float*)d_out;

    repack_kernel<<<dim3((352256 + 255) / 256), 256, 0, stream>>>(
        start_w, filter_w, gate_w, residual_w, skip_w, end1_w, end2_w, ws);

    const size_t need = (size_t)OFF_CNT * 4 + (size_t)NBAR * 8 * 4;
    bool coop_ok = false;
    if (ws_size >= need) {
        hipMemsetAsync((char*)d_ws + (size_t)OFF_CNT * 4, 0, NBAR * 8 * 4, stream);
        void* args[] = { (void*)&x_input, (void*)&ws, (void*)&end1_b,
                         (void*)&end2_b, (void*)&out };
        hipError_t err = hipLaunchCooperativeKernel((const void*)wavenet_all,
                                                    dim3(1024), dim3(256), args, 0, stream);
        if (err != hipSuccess)
            err = hipLaunchCooperativeKernel((const void*)wavenet_all,
                                             dim3(512), dim3(256), args, 0, stream);
        coop_ok = (err == hipSuccess);
    }

    if (!coop_ok) {
        // r5 fallback (verified): per-layer sequence
        start_kernel<<<dim3(128, NB), dim3(64, 8), 0, stream>>>(
            x_input, ws + OFF_ST, ws + OFF_XA);
        float* bufs[2] = { ws + OFF_XA, ws + OFF_XB };
        int cur = 0;
        int Tin = T0;
        int cnt2 = 0;
        for (int bl = 0; bl < 4; bl++) {
            int dd = 1;
            for (int i = 0; i < 10; i++) {
                int Tout_l = Tin - dd;
                layer_kernel<<<dim3((Tout_l + 63) / 64, NB), dim3(64, 8), 0, stream>>>(
                    bufs[cur], bufs[cur ^ 1], ws + OFF_WBLOB + (size_t)cnt2 * 5120,
                    dd, Tout_l, cnt2 == 39);
                cur ^= 1;
                Tin = Tout_l;
                dd *= 2;
                cnt2++;
            }
        }
        skip_kernel<<<dim3(64, NB), dim3(64, 8), 0, stream>>>(bufs[cur], ws + OFF_SK, ws + OFF_H1);
        end1_kernel<<<dim3(64, NB), dim3(64, 8), 0, stream>>>(ws + OFF_H1, ws + OFF_E1T, end1_b, ws + OFF_E1);
        end2_kernel<<<dim3(64, NB), dim3(64, 8), 0, stream>>>(ws + OFF_E1, ws + OFF_E2T, end2_b, out);
    }
}